// Round 13
// baseline (93.055 us; speedup 1.0000x reference)
//
#include <hip/hip_runtime.h>
#include <cstdint>

typedef unsigned long long u64;

#define TOPK 2048          // candidate window for mask+scan
#define MW2 (TOPK / 64)    // 32 suppression words
#define CAND 4096          // max compacted candidates (sort size)
#define HIST_BLOCKS 16
#define COMPACT_BLOCKS 32
#define FB_WORDS 1024      // fallback alive-bitmap capacity (64K boxes)

// meta layout (ints): [0]=ticket [1]=validTotal [2]=Msel [3]=flag2

__device__ __forceinline__ unsigned score_ud(float s, float thr) {
    unsigned u = __float_as_uint(s);
    u ^= (u >> 31) ? 0xFFFFFFFFu : 0x80000000u;   // orderable ascending
    unsigned ud = ~u;                              // ascending ud = descending score
    if (!(s > thr)) ud = 0xFFFFFFFFu;              // below threshold -> invalid
    return ud;
}

// ---- 1. histogram: per-block private slice (no global atomics); block0 zeros ticket ----
__global__ __launch_bounds__(256) void hist_kernel(const float* __restrict__ scores,
                                                   const float* __restrict__ thrPtr,
                                                   int* __restrict__ slices,
                                                   int* __restrict__ meta, int N) {
    __shared__ int h[4096];
    int tid = threadIdx.x;
    for (int b = tid; b < 4096; b += 256) h[b] = 0;
    if (blockIdx.x == 0 && tid == 0) meta[0] = 0;   // compact ticket
    __syncthreads();
    float thr = *thrPtr;
    for (int i = blockIdx.x * 256 + tid; i < N; i += HIST_BLOCKS * 256) {
        unsigned ud = score_ud(scores[i], thr);
        if (ud != 0xFFFFFFFFu) atomicAdd(&h[ud >> 20], 1);
    }
    __syncthreads();
    int* myslice = slices + blockIdx.x * 4096;
    for (int b = tid; b < 4096; b += 256) myslice[b] = h[b];
}

// ---- 2. compact with inline cutoff (vectorized slice-reduce, wave-agg ticket) ----
__global__ __launch_bounds__(256) void compact_kernel(
        const float* __restrict__ scores, const float* __restrict__ thrPtr,
        const int* __restrict__ slices, int* __restrict__ meta,
        u64* __restrict__ ckeys, int N, int maxNeed) {
    __shared__ int bins[4096];
    __shared__ int shC;
    int tid = threadIdx.x, lane = tid & 63;
    // phase A: sum the 16 per-block slices; int4, fully unrolled (ILP)
    {
        const int4* sl = (const int4*)slices;     // [HIST_BLOCKS][1024] int4
        int4* bo = (int4*)bins;                   // [1024] int4
#pragma unroll
        for (int k = 0; k < 4; ++k) {
            int p = k * 256 + tid;
            int ax = 0, ay = 0, az = 0, aw = 0;
#pragma unroll
            for (int s = 0; s < HIST_BLOCKS; ++s) {
                int4 v = sl[s * 1024 + p];
                ax += v.x; ay += v.y; az += v.z; aw += v.w;
            }
            int4 o; o.x = ax; o.y = ay; o.z = az; o.w = aw;
            bo[p] = o;
        }
    }
    __syncthreads();
    // phase B: wave0 computes cutoff C (bank-rotated LDS reads)
    if (tid < 64) {
        int base = lane * 64;
        int sum = 0;
        for (int b = 0; b < 64; ++b) sum += bins[base + ((b + lane) & 63)];
        int incl = sum;
        for (int off = 1; off < 64; off <<= 1) {
            int o = __shfl_up(incl, off, 64);
            if (lane >= off) incl += o;
        }
        int total = __shfl(incl, 63, 64);
        int need = (maxNeed < total) ? maxNeed : total;
        u64 ok = __ballot(incl >= need);               // nonzero when need>0
        int L = (ok != 0ull) ? (int)__builtin_ctzll(ok) : 0;
        if (lane == L) {
            int acc = incl - sum;                      // exclusive prefix
            int C = base, Msel = acc;
            for (int b = 0; b < 64; ++b) {
                acc += bins[base + b];
                if (acc >= need) { C = base + b; Msel = acc; break; }
            }
            if (need <= 0) { C = -1; Msel = 0; }
            shC = C;
            if (blockIdx.x == 0) {
                meta[2] = Msel;
                meta[3] = (Msel > CAND) ? 1 : 0;
            }
        }
        if (lane == 0 && blockIdx.x == 0) meta[1] = total;
    }
    __syncthreads();
    // phase C: grid-stride compaction, per-wave aggregated ticket
    int C = shC;
    float thr = *thrPtr;
    for (int i0 = blockIdx.x * 256; i0 < N; i0 += COMPACT_BLOCKS * 256) {
        int i = i0 + tid;
        bool sel = false;
        unsigned ud = 0;
        if (i < N) {
            ud = score_ud(scores[i], thr);
            sel = (ud != 0xFFFFFFFFu) && ((int)(ud >> 20) <= C);
        }
        u64 ball = __ballot(sel);
        if (ball) {
            int cntw = __popcll(ball);
            int base = 0;
            if (lane == 0) base = atomicAdd(&meta[0], cntw);
            base = __shfl(base, 0, 64);
            if (sel) {
                int slot = base + __popcll(ball & ((1ull << lane) - 1ull));
                if (slot < CAND) ckeys[slot] = ((u64)ud << 32) | (unsigned)i;
            }
        }
    }
}

// ---- 3. sort: bitonic network rescheduled wave-local (R9-proven) ----
template<int K>
__device__ __forceinline__ void wave_chain(u64 (&r)[4], int wave, int lane) {
    if (K >= 256) {                            // j = 128: pairs (e, e+2)
#pragma unroll
        for (int e = 0; e < 2; ++e) {
            bool up = ((((wave << 8) | (e << 6) | lane) & K) == 0);
            if ((r[e] > r[e + 2]) == up) { u64 tmp = r[e]; r[e] = r[e + 2]; r[e + 2] = tmp; }
        }
    }
    if (K >= 128) {                            // j = 64: pairs (e, e+1)
#pragma unroll
        for (int e = 0; e < 4; e += 2) {
            bool up = ((((wave << 8) | (e << 6) | lane) & K) == 0);
            if ((r[e] > r[e + 1]) == up) { u64 tmp = r[e]; r[e] = r[e + 1]; r[e + 1] = tmp; }
        }
    }
#pragma unroll
    for (int j = 32; j >= 1; j >>= 1) {        // j <= 32: shfl within wave
        if (2 * j <= K) {
#pragma unroll
            for (int e = 0; e < 4; ++e) {
                bool up = ((((wave << 8) | (e << 6) | lane) & K) == 0);
                u64 o = __shfl_xor(r[e], j, 64);
                bool lower = ((lane & j) == 0);
                bool keepMin = (up == lower);
                u64 mn = (r[e] < o) ? r[e] : o;
                u64 mx = (r[e] < o) ? o : r[e];
                r[e] = keepMin ? mn : mx;
            }
        }
    }
}

__global__ __launch_bounds__(1024) void sort_gather_kernel(
        const u64* __restrict__ ckeys, const int* __restrict__ meta,
        const float* __restrict__ boxes,
        float* __restrict__ sx1, float* __restrict__ sy1,
        float* __restrict__ sx2, float* __restrict__ sy2,
        float* __restrict__ areas, int* __restrict__ sorig,
        u64* __restrict__ validw) {
    __shared__ u64 lk[CAND];
    int tid = threadIdx.x, lane = tid & 63, wave = tid >> 6;
    int M = meta[2];
    if (M > CAND) M = CAND;
    u64 r[4];
#pragma unroll
    for (int e = 0; e < 4; ++e) {
        int s = (wave << 8) + (e << 6) + lane;
        r[e] = (s < M) ? ckeys[s] : ~0ull;
    }
    wave_chain<2>(r, wave, lane);
    wave_chain<4>(r, wave, lane);
    wave_chain<8>(r, wave, lane);
    wave_chain<16>(r, wave, lane);
    wave_chain<32>(r, wave, lane);
    wave_chain<64>(r, wave, lane);
    wave_chain<128>(r, wave, lane);
    wave_chain<256>(r, wave, lane);
#pragma unroll
    for (int lvl = 0; lvl < 4; ++lvl) {
        const int K = 512 << lvl;
#pragma unroll
        for (int e = 0; e < 4; ++e) lk[(wave << 8) + (e << 6) + lane] = r[e];
        __syncthreads();
        for (int j = K / 2; j >= 256; j >>= 1) {
            for (int p = tid; p < CAND / 2; p += 1024) {
                int i = ((p & ~(j - 1)) << 1) | (p & (j - 1));
                int l = i + j;
                bool up = ((i & K) == 0);
                u64 a = lk[i], b = lk[l];
                if ((a > b) == up) { lk[i] = b; lk[l] = a; }
            }
            __syncthreads();
        }
#pragma unroll
        for (int e = 0; e < 4; ++e) r[e] = lk[(wave << 8) + (e << 6) + lane];
        switch (lvl) {
            case 0: wave_chain<512>(r, wave, lane); break;
            case 1: wave_chain<1024>(r, wave, lane); break;
            case 2: wave_chain<2048>(r, wave, lane); break;
            default: wave_chain<4096>(r, wave, lane); break;
        }
    }
    if (wave < (TOPK / 256)) {
#pragma unroll
        for (int e = 0; e < 4; ++e) {
            int s = (wave << 8) + (e << 6) + lane;
            u64 k = r[e];
            unsigned hi = (unsigned)(k >> 32), lo = (unsigned)k;
            bool valid = (hi != 0xFFFFFFFFu);
            u64 ball = __ballot(valid);
            if (lane == 0) validw[s >> 6] = ball;
            float4 b; b.x = 0.f; b.y = 0.f; b.z = 0.f; b.w = 0.f;
            if (valid) b = ((const float4*)boxes)[lo];
            sx1[s] = b.x; sy1[s] = b.y; sx2[s] = b.z; sy2[s] = b.w;
            areas[s] = (b.z - b.x) * (b.w - b.y);
            sorig[s] = valid ? (int)lo : 0;
        }
    }
}

// ---- 4. transposed IoU mask: maskT[j][wi] = rows in chunk wi that suppress j ----
__global__ __launch_bounds__(64) void mask2_kernel(
        const float* __restrict__ sx1, const float* __restrict__ sy1,
        const float* __restrict__ sx2, const float* __restrict__ sy2,
        const float* __restrict__ areas, const float* __restrict__ iouThrPtr,
        u64* __restrict__ maskT, u64* __restrict__ diagT) {
    int wi = blockIdx.x, wj = blockIdx.y;
    if (wj < wi) return;                       // uniform block exit, before barriers
    __shared__ float jx1[64], jy1[64], jx2[64], jy2[64], ja[64];
    __shared__ u64 rowLDS[64];
    int t = threadIdx.x;
    int j0 = wj << 6;
    jx1[t] = sx1[j0 + t]; jy1[t] = sy1[j0 + t];
    jx2[t] = sx2[j0 + t]; jy2[t] = sy2[j0 + t];
    ja[t] = areas[j0 + t];
    __syncthreads();
    int i = (wi << 6) + t;
    float thr = *iouThrPtr;
    float ix1 = sx1[i], iy1 = sy1[i], ix2 = sx2[i], iy2 = sy2[i], ia = areas[i];
    u64 bits = 0;
    for (int jj = 0; jj < 64; ++jj) {
        int j = j0 + jj;
        if (j > i) {
            float xx1 = fmaxf(ix1, jx1[jj]);
            float yy1 = fmaxf(iy1, jy1[jj]);
            float xx2 = fminf(ix2, jx2[jj]);
            float yy2 = fminf(iy2, jy2[jj]);
            float ww = fmaxf(xx2 - xx1, 0.0f);
            float hh = fmaxf(yy2 - yy1, 0.0f);
            float inter = ww * hh;
            float uni = fmaxf(ia + ja[jj] - inter, 1e-6f);
            if (inter / uni >= thr) bits |= 1ull << jj;
        }
    }
    rowLDS[t] = bits;
    __syncthreads();
    u64 col = 0;
    for (int r = 0; r < 64; ++r) col |= ((rowLDS[r] >> t) & 1ull) << r;
    maskT[(size_t)(j0 + t) * MW2 + wi] = col;
    if (wi == wj) diagT[(wi << 6) + t] = col;
}

// ---- 5. scan: single-wave zero-barrier loop + inline exact fallback ----
__global__ __launch_bounds__(1024) void scan2_kernel(
        const u64* __restrict__ maskT, const u64* __restrict__ diagT,
        const u64* __restrict__ validw, const int* __restrict__ sorig,
        const int* __restrict__ meta,
        const float* __restrict__ boxes, const float* __restrict__ scores,
        const float* __restrict__ iouThrPtr, const float* __restrict__ scoreThrPtr,
        int* __restrict__ out, int N, int maxOut) {
    __shared__ u64 diagLDS[TOPK];
    __shared__ u64 selw[MW2];
    __shared__ u64 validwLDS[MW2];
    __shared__ int selLDS[TOPK];
    __shared__ int cntSh;
    __shared__ int validScanSh;
    __shared__ u64 aliveW[FB_WORDS];
    __shared__ u64 keyRed[16];
    __shared__ u64 winKeySh;
    int tid = threadIdx.x, lane = tid & 63, wave = tid >> 6;

    for (int k = tid; k < TOPK; k += 1024) diagLDS[k] = diagT[k];
    if (tid < MW2) { selw[tid] = 0ull; validwLDS[tid] = validw[tid]; }
    if (tid == 0) { cntSh = 0; validScanSh = 0; }
    __syncthreads();

    if (wave == 0) {
        // per-lane suppression column buffers (32 u64 = 16 ulonglong2 each), ping-pong
        ulonglong2 A[16], B[16];
#define LOADCOL(BUF, W)                                                          \
        {                                                                        \
            const ulonglong2* p =                                                \
                (const ulonglong2*)(maskT + (size_t)(((W) << 6) | lane) * MW2);  \
            _Pragma("unroll")                                                    \
            for (int k = 0; k < 16; ++k) BUF[k] = p[k];                          \
        }
#define PROCESS(BUF, W)                                                          \
        {                                                                        \
            u64 kill = 0;                                                        \
            _Pragma("unroll")                                                    \
            for (int k = 0; k < 16; ++k)                                         \
                kill |= (BUF[k].x & selw[2 * k]) | (BUF[k].y & selw[2 * k + 1]); \
            bool alv = ((validwLDS[W] >> lane) & 1ull) && (kill == 0ull);        \
            u64 inm = diagLDS[((W) << 6) | lane];                                \
            u64 sel = __ballot(alv);                                             \
            for (int it = 0; it < 64; ++it) {                                    \
                bool killed = (inm & sel) != 0ull;                               \
                u64 ns = __ballot(alv && !killed);                               \
                if (ns == sel) break;                                            \
                sel = ns;                                                        \
            }                                                                    \
            int room = maxOut - cnt;                                             \
            int tot = __popcll(sel);                                             \
            u64 below = (1ull << lane) - 1ull;                                   \
            if (tot > room) {                                                    \
                bool keep = ((sel >> lane) & 1ull) &&                            \
                            (__popcll(sel & below) < room);                      \
                sel = __ballot(keep);                                            \
                tot = room;                                                      \
            }                                                                    \
            if ((sel >> lane) & 1ull) {                                          \
                int pos = cnt + __popcll(sel & below);                           \
                selLDS[pos] = ((W) << 6) | lane;                                 \
            }                                                                    \
            if (lane == 0) selw[W] = sel;                                        \
            cnt += tot;                                                          \
            done = (cnt >= maxOut);                                              \
        }
        int cnt = 0;
        bool done = false;
        LOADCOL(A, 0);
        for (int w = 0; w < MW2 && !done; w += 2) {
            if (w + 1 < MW2) LOADCOL(B, w + 1);
            PROCESS(A, w);
            if (done || w + 1 >= MW2) break;
            if (w + 2 < MW2) LOADCOL(A, w + 2);
            PROCESS(B, w + 1);
        }
#undef LOADCOL
#undef PROCESS
        if (lane == 0) cntSh = cnt;
    }
    __syncthreads();

    if (tid < MW2) atomicAdd(&validScanSh, __popcll(validwLDS[tid]));
    __syncthreads();
    int cnt = cntSh;
    int vt = meta[1];
    int f2 = meta[3];
    bool complete = (f2 == 0) && ((cnt >= maxOut) || (validScanSh >= vt));
    if (complete) {                            // uniform
        for (int k = tid; k < cnt; k += 1024) out[k] = sorig[selLDS[k]];
        for (int k = cnt + tid; k < maxOut; k += 1024) out[k] = 0;
        if (tid == 0) out[maxOut] = cnt;
        return;                                // uniform return
    }

    // ---- exact fallback: repeated argmax greedy NMS (R8-proven body) ----
    float sThr = *scoreThrPtr, iThr = *iouThrPtr;
    for (int e0 = wave << 6; e0 < N; e0 += 1024) {
        int e = e0 + lane;
        bool a = (e < N) && (scores[e] > sThr);
        u64 ball = __ballot(a);
        if (lane == 0) aliveW[e0 >> 6] = ball;
    }
    __syncthreads();
    int fcnt = 0;
    while (fcnt < maxOut) {
        u64 best = 0;
        for (int e = tid; e < N; e += 1024) {
            if ((aliveW[e >> 6] >> (e & 63)) & 1ull) {
                float s = scores[e];
                unsigned u = __float_as_uint(s);
                u ^= (u >> 31) ? 0xFFFFFFFFu : 0x80000000u;
                u64 k = ((u64)u << 32) | (unsigned)(~e);
                if (k > best) best = k;
            }
        }
#pragma unroll
        for (int off = 32; off >= 1; off >>= 1) {
            u64 o = __shfl_xor(best, off, 64);
            if (o > best) best = o;
        }
        if (lane == 0) keyRed[wave] = best;
        __syncthreads();
        if (tid == 0) {
            u64 b = 0;
            for (int p = 0; p < 16; ++p) if (keyRed[p] > b) b = keyRed[p];
            winKeySh = b;
        }
        __syncthreads();
        u64 wk = winKeySh;
        if (wk == 0ull) break;
        int win = (int)(~(unsigned)wk);
        if (tid == 0) out[fcnt] = win;
        ++fcnt;
        float4 wb = ((const float4*)boxes)[win];
        float wa = (wb.z - wb.x) * (wb.w - wb.y);
        for (int e0 = wave << 6; e0 < N; e0 += 1024) {
            int e = e0 + lane;
            bool kill = false;
            if (e < N && ((aliveW[e0 >> 6] >> lane) & 1ull)) {
                if (e == win) kill = true;
                else {
                    float4 bb = ((const float4*)boxes)[e];
                    float xx1 = fmaxf(wb.x, bb.x), yy1 = fmaxf(wb.y, bb.y);
                    float xx2 = fminf(wb.z, bb.z), yy2 = fminf(wb.w, bb.w);
                    float inter = fmaxf(xx2 - xx1, 0.0f) * fmaxf(yy2 - yy1, 0.0f);
                    float ba = (bb.z - bb.x) * (bb.w - bb.y);
                    float uni = fmaxf(wa + ba - inter, 1e-6f);
                    kill = (inter / uni >= iThr);
                }
            }
            u64 kb = __ballot(kill);
            if (lane == 0 && kb) aliveW[e0 >> 6] &= ~kb;
        }
        __syncthreads();
    }
    for (int k = fcnt + tid; k < maxOut; k += 1024) out[k] = 0;
    if (tid == 0) out[maxOut] = fcnt;
}

// ---------------- launch ----------------
extern "C" void kernel_launch(void* const* d_in, const int* in_sizes, int n_in,
                              void* d_out, int out_size, void* d_ws, size_t ws_size,
                              hipStream_t stream) {
    const float* boxes       = (const float*)d_in[0];
    const float* scores      = (const float*)d_in[1];
    const float* iouThrPtr   = (const float*)d_in[3];
    const float* scoreThrPtr = (const float*)d_in[4];

    int N = in_sizes[0] / 4;
    int maxOut = out_size - 1;

    char* ws = (char*)d_ws;
    size_t off = 0;
    auto take = [&](size_t b) { void* p = ws + off; off = (off + b + 255) & ~(size_t)255; return p; };
    int*   slices = (int*)  take((size_t)HIST_BLOCKS * 4096 * 4);
    int*   meta   = (int*)  take(256);
    u64*   ckeys  = (u64*)  take((size_t)CAND * 8);
    float* sx1    = (float*)take(TOPK * 4);
    float* sy1    = (float*)take(TOPK * 4);
    float* sx2    = (float*)take(TOPK * 4);
    float* sy2    = (float*)take(TOPK * 4);
    float* areas  = (float*)take(TOPK * 4);
    int*   sorig  = (int*)  take(TOPK * 4);
    u64*   validw = (u64*)  take(MW2 * 8);
    u64*   maskT  = (u64*)  take((size_t)TOPK * MW2 * 8);
    u64*   diagT  = (u64*)  take((size_t)MW2 * 64 * 8);
    (void)ws_size;

    hist_kernel<<<HIST_BLOCKS, 256, 0, stream>>>(scores, scoreThrPtr, slices, meta, N);
    compact_kernel<<<COMPACT_BLOCKS, 256, 0, stream>>>(scores, scoreThrPtr, slices, meta,
                                                       ckeys, N, TOPK);
    sort_gather_kernel<<<1, 1024, 0, stream>>>(ckeys, meta, boxes, sx1, sy1, sx2, sy2,
                                               areas, sorig, validw);
    mask2_kernel<<<dim3(MW2, MW2), 64, 0, stream>>>(sx1, sy1, sx2, sy2, areas, iouThrPtr,
                                                    maskT, diagT);
    scan2_kernel<<<1, 1024, 0, stream>>>(maskT, diagT, validw, sorig, meta,
                                         boxes, scores, iouThrPtr, scoreThrPtr,
                                         (int*)d_out, N, maxOut);
}

// Round 14
// 64.540 us; speedup vs baseline: 1.4418x; 1.4418x over previous
//
#include <hip/hip_runtime.h>
#include <cstdint>

typedef unsigned long long u64;

#define TOPK 2048          // candidate window for mask+scan
#define MW2 (TOPK / 64)    // 32 suppression words
#define CAND 4096          // max compacted candidates
#define HIST_BLOCKS 8
#define COMPACT_BLOCKS 32
#define RANK_BLOCKS (CAND / 64)
#define FB_WORDS 1024      // fallback alive-bitmap capacity (64K boxes)

// meta layout (ints): [0]=ticket [1]=validTotal [2]=Msel [3]=flag2

__device__ __forceinline__ unsigned score_ud(float s, float thr) {
    unsigned u = __float_as_uint(s);
    u ^= (u >> 31) ? 0xFFFFFFFFu : 0x80000000u;   // orderable ascending
    unsigned ud = ~u;                              // ascending ud = descending score
    if (!(s > thr)) ud = 0xFFFFFFFFu;              // below threshold -> invalid
    return ud;
}

// ---- 1. histogram: per-block private slice (R11-proven) ----
__global__ __launch_bounds__(256) void hist_kernel(const float* __restrict__ scores,
                                                   const float* __restrict__ thrPtr,
                                                   int* __restrict__ slices,
                                                   int* __restrict__ meta, int N) {
    __shared__ int h[4096];
    int tid = threadIdx.x;
    for (int b = tid; b < 4096; b += 256) h[b] = 0;
    if (blockIdx.x == 0 && tid == 0) meta[0] = 0;   // compact ticket
    __syncthreads();
    float thr = *thrPtr;
    for (int i = blockIdx.x * 256 + tid; i < N; i += HIST_BLOCKS * 256) {
        unsigned ud = score_ud(scores[i], thr);
        if (ud != 0xFFFFFFFFu) atomicAdd(&h[ud >> 20], 1);
    }
    __syncthreads();
    int* myslice = slices + blockIdx.x * 4096;
    for (int b = tid; b < 4096; b += 256) myslice[b] = h[b];
}

// ---- 2. compact with inline cutoff (R11-proven) ----
__global__ __launch_bounds__(256) void compact_kernel(
        const float* __restrict__ scores, const float* __restrict__ thrPtr,
        const int* __restrict__ slices, int* __restrict__ meta,
        u64* __restrict__ ckeys, int N, int maxNeed) {
    __shared__ int bins[4096];
    __shared__ int shC;
    int tid = threadIdx.x, lane = tid & 63;
    // phase A: sum the 8 per-block slices; int4, fully unrolled (ILP)
    {
        const int4* sl = (const int4*)slices;     // [HIST_BLOCKS][1024] int4
        int4* bo = (int4*)bins;                   // [1024] int4
#pragma unroll
        for (int k = 0; k < 4; ++k) {
            int p = k * 256 + tid;
            int4 a = sl[p];
            int4 v1 = sl[1024 + p];
            int4 v2 = sl[2 * 1024 + p];
            int4 v3 = sl[3 * 1024 + p];
            int4 v4 = sl[4 * 1024 + p];
            int4 v5 = sl[5 * 1024 + p];
            int4 v6 = sl[6 * 1024 + p];
            int4 v7 = sl[7 * 1024 + p];
            a.x += v1.x + v2.x + v3.x + v4.x + v5.x + v6.x + v7.x;
            a.y += v1.y + v2.y + v3.y + v4.y + v5.y + v6.y + v7.y;
            a.z += v1.z + v2.z + v3.z + v4.z + v5.z + v6.z + v7.z;
            a.w += v1.w + v2.w + v3.w + v4.w + v5.w + v6.w + v7.w;
            bo[p] = a;
        }
    }
    __syncthreads();
    // phase B: wave0 computes cutoff C (bank-rotated LDS reads)
    if (tid < 64) {
        int base = lane * 64;
        int sum = 0;
        for (int b = 0; b < 64; ++b) sum += bins[base + ((b + lane) & 63)];
        int incl = sum;
        for (int off = 1; off < 64; off <<= 1) {
            int o = __shfl_up(incl, off, 64);
            if (lane >= off) incl += o;
        }
        int total = __shfl(incl, 63, 64);
        int need = (maxNeed < total) ? maxNeed : total;
        u64 ok = __ballot(incl >= need);
        int L = (ok != 0ull) ? (int)__builtin_ctzll(ok) : 0;
        if (lane == L) {
            int acc = incl - sum;                      // exclusive prefix
            int C = base, Msel = acc;
            for (int b = 0; b < 64; ++b) {
                acc += bins[base + b];
                if (acc >= need) { C = base + b; Msel = acc; break; }
            }
            if (need <= 0) { C = -1; Msel = 0; }
            shC = C;
            if (blockIdx.x == 0) {
                meta[2] = Msel;
                meta[3] = (Msel > CAND) ? 1 : 0;
            }
        }
        if (lane == 0 && blockIdx.x == 0) meta[1] = total;
    }
    __syncthreads();
    // phase C: grid-stride compaction, per-wave aggregated ticket
    int C = shC;
    float thr = *thrPtr;
    for (int i0 = blockIdx.x * 256; i0 < N; i0 += COMPACT_BLOCKS * 256) {
        int i = i0 + tid;
        bool sel = false;
        unsigned ud = 0;
        if (i < N) {
            ud = score_ud(scores[i], thr);
            sel = (ud != 0xFFFFFFFFu) && ((int)(ud >> 20) <= C);
        }
        u64 ball = __ballot(sel);
        if (ball) {
            int cntw = __popcll(ball);
            int base = 0;
            if (lane == 0) base = atomicAdd(&meta[0], cntw);
            base = __shfl(base, 0, 64);
            if (sel) {
                int slot = base + __popcll(ball & ((1ull << lane) - 1ull));
                if (slot < CAND) ckeys[slot] = ((u64)ud << 32) | (unsigned)i;
            }
        }
    }
}

// ---- 3. rank-and-gather: rank = #{keys < mine}; exact permutation, no sort ----
__global__ __launch_bounds__(256) void rank_gather_kernel(
        const u64* __restrict__ ckeys, const int* __restrict__ meta,
        const float* __restrict__ boxes,
        float4* __restrict__ sboxes, int* __restrict__ sorig) {
    __shared__ u64 lk[CAND];
    __shared__ int part[4][64];
    int tid = threadIdx.x, lane = tid & 63, q = tid >> 6;
    int Msel = meta[2];
    if (Msel > CAND) Msel = CAND;
    for (int j = tid; j < Msel; j += 256) lk[j] = ckeys[j];
    __syncthreads();
    if (blockIdx.x * 64 >= Msel) return;          // uniform (blockIdx, Msel uniform)
    int i = blockIdx.x * 64 + lane;
    u64 key = (i < Msel) ? lk[i] : ~0ull;
    int chunk = (Msel + 3) >> 2;
    int j0 = q * chunk;
    int j1 = j0 + chunk; if (j1 > Msel) j1 = Msel;
    int r = 0;
#pragma unroll 4
    for (int j = j0; j < j1; ++j) r += (lk[j] < key) ? 1 : 0;
    part[q][lane] = r;
    __syncthreads();
    if (q == 0 && i < Msel) {
        int rank = part[0][lane] + part[1][lane] + part[2][lane] + part[3][lane];
        if (rank < TOPK) {
            int idx = (int)(key & 0xFFFFFFFFu);
            sboxes[rank] = ((const float4*)boxes)[idx];
            sorig[rank] = idx;
        }
    }
}

// ---- 4. transposed IoU mask: maskT[j][wi] = rows in chunk wi that suppress j ----
__global__ __launch_bounds__(64) void mask2_kernel(
        const float4* __restrict__ sboxes, const float* __restrict__ iouThrPtr,
        u64* __restrict__ maskT, u64* __restrict__ diagT) {
    int wi = blockIdx.x, wj = blockIdx.y;
    if (wj < wi) return;                       // uniform block exit, before barriers
    __shared__ float jx1[64], jy1[64], jx2[64], jy2[64], ja[64];
    __shared__ u64 rowLDS[64];
    int t = threadIdx.x;
    int j0 = wj << 6;
    float4 jb = sboxes[j0 + t];
    jx1[t] = jb.x; jy1[t] = jb.y; jx2[t] = jb.z; jy2[t] = jb.w;
    ja[t] = (jb.z - jb.x) * (jb.w - jb.y);
    __syncthreads();
    int i = (wi << 6) + t;
    float thr = *iouThrPtr;
    float4 ib = sboxes[i];
    float ia = (ib.z - ib.x) * (ib.w - ib.y);
    u64 bits = 0;
    for (int jj = 0; jj < 64; ++jj) {
        int j = j0 + jj;
        if (j > i) {
            float xx1 = fmaxf(ib.x, jx1[jj]);
            float yy1 = fmaxf(ib.y, jy1[jj]);
            float xx2 = fminf(ib.z, jx2[jj]);
            float yy2 = fminf(ib.w, jy2[jj]);
            float ww = fmaxf(xx2 - xx1, 0.0f);
            float hh = fmaxf(yy2 - yy1, 0.0f);
            float inter = ww * hh;
            float uni = fmaxf(ia + ja[jj] - inter, 1e-6f);
            if (inter / uni >= thr) bits |= 1ull << jj;
        }
    }
    rowLDS[t] = bits;                          // row i over columns of chunk wj
    __syncthreads();
    u64 col = 0;                               // transpose: column (j0+t) over rows of chunk wi
    for (int r = 0; r < 64; ++r) col |= ((rowLDS[r] >> t) & 1ull) << r;
    maskT[(size_t)(j0 + t) * MW2 + wi] = col;
    if (wi == wj) diagT[(wi << 6) + t] = col;
}

// ---- 5. chunk-wise greedy scan (R12-proven 256-thread core) + inline fallback ----
__global__ __launch_bounds__(1024) void scan2_kernel(
        const u64* __restrict__ maskT, const u64* __restrict__ diagT,
        const int* __restrict__ sorig, const int* __restrict__ meta,
        const float* __restrict__ boxes, const float* __restrict__ scores,
        const float* __restrict__ iouThrPtr, const float* __restrict__ scoreThrPtr,
        int* __restrict__ out, int N, int maxOut) {
    __shared__ u64 diagLDS[TOPK];
    __shared__ u64 selw[MW2];
    __shared__ u64 validwLDS[MW2];
    __shared__ u64 ballots[4];
    __shared__ int selLDS[TOPK];
    __shared__ int cntSh;
    __shared__ u64 aliveW[FB_WORDS];
    __shared__ u64 keyRed[16];
    __shared__ u64 winKeySh;
    int tid = threadIdx.x, lane = tid & 63, wave = tid >> 6;

    int Msel = meta[2];
    int V = (Msel < TOPK) ? Msel : TOPK;           // valid = ranks [0, V)
    for (int k = tid; k < TOPK; k += 1024) diagLDS[k] = diagT[k];
    if (tid < MW2) {
        int lo = tid * 64;
        u64 vw = (V >= lo + 64) ? ~0ull : ((V > lo) ? ((1ull << (V - lo)) - 1ull) : 0ull);
        validwLDS[tid] = vw;
        selw[tid] = 0ull;
    }
    if (tid == 0) cntSh = 0;

    ulonglong2 a0, a1, a2, a3;
    int cc = tid >> 2, g = tid & 3;
    if (tid < 256) {
        const ulonglong2* p = (const ulonglong2*)(maskT + (size_t)cc * MW2 + g * 8);
        a0 = p[0]; a1 = p[1]; a2 = p[2]; a3 = p[3];
    }
    __syncthreads();

    int cnt = 0;
    for (int w = 0; w < MW2; ++w) {
        if (tid < 256) {
            u64 wd0 = a0.x, wd1 = a0.y, wd2 = a1.x, wd3 = a1.y;
            u64 wd4 = a2.x, wd5 = a2.y, wd6 = a3.x, wd7 = a3.y;
            int wr0 = g * 8;
            u64 acc = 0;
            if (wr0 + 0 < w) acc |= wd0 & selw[wr0 + 0];
            if (wr0 + 1 < w) acc |= wd1 & selw[wr0 + 1];
            if (wr0 + 2 < w) acc |= wd2 & selw[wr0 + 2];
            if (wr0 + 3 < w) acc |= wd3 & selw[wr0 + 3];
            if (wr0 + 4 < w) acc |= wd4 & selw[wr0 + 4];
            if (wr0 + 5 < w) acc |= wd5 & selw[wr0 + 5];
            if (wr0 + 6 < w) acc |= wd6 & selw[wr0 + 6];
            if (wr0 + 7 < w) acc |= wd7 & selw[wr0 + 7];
            acc |= __shfl_xor(acc, 1, 64);
            acc |= __shfl_xor(acc, 2, 64);
            u64 B = __ballot(acc != 0ull);
            if (lane == 0) ballots[wave] = B;
            if (w + 1 < MW2) {
                const ulonglong2* p = (const ulonglong2*)(maskT + (size_t)((w + 1) * 64 + cc) * MW2 + g * 8);
                a0 = p[0]; a1 = p[1]; a2 = p[2]; a3 = p[3];
            }
        }
        __syncthreads();
        if (wave == 0) {
            u64 bv = ballots[lane >> 4];
            bool crossk = (bv >> ((lane & 15) << 2)) & 1ull;
            bool alv = ((validwLDS[w] >> lane) & 1ull) && !crossk;
            u64 inm = diagLDS[(w << 6) | lane];
            u64 sel = __ballot(alv);
            for (int it = 0; it < 64; ++it) {  // fixpoint; bounded (monotone shrink)
                bool killed = (inm & sel) != 0ull;
                u64 ns = __ballot(alv && !killed);
                if (ns == sel) break;
                sel = ns;
            }
            int room = maxOut - cnt;
            int tot = __popcll(sel);
            u64 below = (1ull << lane) - 1ull;
            if (tot > room) {
                bool keep = ((sel >> lane) & 1ull) && (__popcll(sel & below) < room);
                sel = __ballot(keep);
                tot = room;
            }
            if ((sel >> lane) & 1ull) {
                int pos = cnt + __popcll(sel & below);
                selLDS[pos] = (w << 6) | lane;
            }
            if (lane == 0) { selw[w] = sel; cntSh = cnt + tot; }
        }
        __syncthreads();
        cnt = cntSh;
        if (cnt >= maxOut) break;
    }

    int vt = meta[1];
    int f2 = meta[3];
    bool complete = (f2 == 0) && ((cnt >= maxOut) || (V >= vt));
    if (complete) {                            // uniform
        for (int k = tid; k < cnt; k += 1024) out[k] = sorig[selLDS[k]];
        for (int k = cnt + tid; k < maxOut; k += 1024) out[k] = 0;
        if (tid == 0) out[maxOut] = cnt;
        return;                                // uniform return
    }

    // ---- exact fallback: repeated argmax greedy NMS (R8-proven body) ----
    float sThr = *scoreThrPtr, iThr = *iouThrPtr;
    for (int e0 = wave << 6; e0 < N; e0 += 1024) {
        int e = e0 + lane;
        bool a = (e < N) && (scores[e] > sThr);
        u64 ball = __ballot(a);
        if (lane == 0) aliveW[e0 >> 6] = ball;
    }
    __syncthreads();
    int fcnt = 0;
    while (fcnt < maxOut) {
        u64 best = 0;
        for (int e = tid; e < N; e += 1024) {
            if ((aliveW[e >> 6] >> (e & 63)) & 1ull) {
                float s = scores[e];
                unsigned u = __float_as_uint(s);
                u ^= (u >> 31) ? 0xFFFFFFFFu : 0x80000000u;
                u64 k = ((u64)u << 32) | (unsigned)(~e);
                if (k > best) best = k;
            }
        }
#pragma unroll
        for (int off = 32; off >= 1; off >>= 1) {
            u64 o = __shfl_xor(best, off, 64);
            if (o > best) best = o;
        }
        if (lane == 0) keyRed[wave] = best;
        __syncthreads();
        if (tid == 0) {
            u64 b = 0;
            for (int p = 0; p < 16; ++p) if (keyRed[p] > b) b = keyRed[p];
            winKeySh = b;
        }
        __syncthreads();
        u64 wk = winKeySh;
        if (wk == 0ull) break;
        int win = (int)(~(unsigned)wk);
        if (tid == 0) out[fcnt] = win;
        ++fcnt;
        float4 wb = ((const float4*)boxes)[win];
        float wa = (wb.z - wb.x) * (wb.w - wb.y);
        for (int e0 = wave << 6; e0 < N; e0 += 1024) {
            int e = e0 + lane;
            bool kill = false;
            if (e < N && ((aliveW[e0 >> 6] >> lane) & 1ull)) {
                if (e == win) kill = true;
                else {
                    float4 bb = ((const float4*)boxes)[e];
                    float xx1 = fmaxf(wb.x, bb.x), yy1 = fmaxf(wb.y, bb.y);
                    float xx2 = fminf(wb.z, bb.z), yy2 = fminf(wb.w, bb.w);
                    float inter = fmaxf(xx2 - xx1, 0.0f) * fmaxf(yy2 - yy1, 0.0f);
                    float ba = (bb.z - bb.x) * (bb.w - bb.y);
                    float uni = fmaxf(wa + ba - inter, 1e-6f);
                    kill = (inter / uni >= iThr);
                }
            }
            u64 kb = __ballot(kill);
            if (lane == 0 && kb) aliveW[e0 >> 6] &= ~kb;
        }
        __syncthreads();
    }
    for (int k = fcnt + tid; k < maxOut; k += 1024) out[k] = 0;
    if (tid == 0) out[maxOut] = fcnt;
}

// ---------------- launch ----------------
extern "C" void kernel_launch(void* const* d_in, const int* in_sizes, int n_in,
                              void* d_out, int out_size, void* d_ws, size_t ws_size,
                              hipStream_t stream) {
    const float* boxes       = (const float*)d_in[0];
    const float* scores      = (const float*)d_in[1];
    const float* iouThrPtr   = (const float*)d_in[3];
    const float* scoreThrPtr = (const float*)d_in[4];

    int N = in_sizes[0] / 4;
    int maxOut = out_size - 1;

    char* ws = (char*)d_ws;
    size_t off = 0;
    auto take = [&](size_t b) { void* p = ws + off; off = (off + b + 255) & ~(size_t)255; return p; };
    int*    slices = (int*)   take((size_t)HIST_BLOCKS * 4096 * 4);
    int*    meta   = (int*)   take(256);
    u64*    ckeys  = (u64*)   take((size_t)CAND * 8);
    float4* sboxes = (float4*)take((size_t)TOPK * 16);
    int*    sorig  = (int*)   take((size_t)TOPK * 4);
    u64*    maskT  = (u64*)   take((size_t)TOPK * MW2 * 8);
    u64*    diagT  = (u64*)   take((size_t)MW2 * 64 * 8);
    (void)ws_size;

    hist_kernel<<<HIST_BLOCKS, 256, 0, stream>>>(scores, scoreThrPtr, slices, meta, N);
    compact_kernel<<<COMPACT_BLOCKS, 256, 0, stream>>>(scores, scoreThrPtr, slices, meta,
                                                       ckeys, N, TOPK);
    rank_gather_kernel<<<RANK_BLOCKS, 256, 0, stream>>>(ckeys, meta, boxes, sboxes, sorig);
    mask2_kernel<<<dim3(MW2, MW2), 64, 0, stream>>>(sboxes, iouThrPtr, maskT, diagT);
    scan2_kernel<<<1, 1024, 0, stream>>>(maskT, diagT, sorig, meta,
                                         boxes, scores, iouThrPtr, scoreThrPtr,
                                         (int*)d_out, N, maxOut);
}